// Round 1
// baseline (247.484 us; speedup 1.0000x reference)
//
#include <hip/hip_runtime.h>

#define HH 192
#define WW 192
#define BATCH 16
#define PLANE (HH*WW)              /* 36864 */
#define NELEM (BATCH*2*PLANE)      /* 1179648 */

// Tile: 96 px wide x 8 rows, 256 threads, 3 px per thread. Halo 2 each side.
// Grid = (2,24,16) = 768 blocks = exactly 3 blocks/CU at launch_bounds(256,3)
// -> perfect per-CU balance (previous 1152 blocks over 1024 slots had a
// ~12.5%-full second round).
#define TILEX 96
#define TILEY 8
#define SW 100  /* TILEX + 4 */
#define SH2 12  /* TILEY + 4 */
#define NSTAGE (2*SH2*SW)   /* 2400 */

// K8T layout: tap-major [25][8] so the 8 per-tap weights are contiguous
// (one s_load_dwordx8). j<6: kernels[j]*DX^-ord; j==6: -K[1] x-flip;
// j==7: -K[2] y-flip.
__global__ void prep_kernel(const float* __restrict__ kern, float* __restrict__ K8T) {
    int t = blockIdx.x * blockDim.x + threadIdx.x;
    if (t >= 200) return;
    const float inv  = 1.0f / 0.0327249f;
    const float inv2 = inv * inv;
    const float sc[6] = {1.0f, inv, inv, inv2, inv2, inv2};
    int o = t / 8, j = t % 8, dy = o / 5, dx = o % 5;
    float v;
    if (j < 6)       v =  kern[j*25 + dy*5 + dx] * sc[j];
    else if (j == 6) v = -kern[1*25 + dy*5 + (4-dx)] * sc[1];
    else             v = -kern[2*25 + (4-dy)*5 + dx] * sc[2];
    K8T[o*8 + j] = v;
}

// One RHS eval fused with axpy: uout = ubase + alpha * rhs(uin).
// 3 px/thread; channels sequential in conv; poly runs all 3 px in lockstep so
// every weight s_load feeds 3 fmas and dep chains interleave (3x ILP).
__global__ __launch_bounds__(256, 3) void rhs_kernel(
    const float* __restrict__ uin,
    const float* __restrict__ ubase,
    float* __restrict__ uout,
    const float* __restrict__ K8T,
    const float* __restrict__ pw0, const float* __restrict__ pb0,
    const float* __restrict__ pw1, const float* __restrict__ pb1,
    const float* __restrict__ pwf, const float* __restrict__ pbf,
    float alpha)
{
    __shared__ float sh[2][SH2][SW];
    const int b   = blockIdx.z;
    const int ty0 = blockIdx.y * TILEY;
    const int tx0 = blockIdx.x * TILEX;
    const int tid = threadIdx.x;

    const float* uin_b = uin + (size_t)b * 2 * PLANE;

    // ---- Staging: 2400 elems over 256 threads (9-10 each). /100 becomes a
    // magic-mul; one-time cost.
    for (int i = tid; i < NSTAGE; i += 256) {
        const int ch  = (i >= SH2*SW) ? 1 : 0;
        const int j   = i - ch * (SH2*SW);
        const int ly  = j / SW;
        const int col = j - ly * SW;
        int gy = ty0 + ly - 2;  if (gy < 0) gy += HH; else if (gy >= HH) gy -= HH;
        int gx = tx0 + col - 2; if (gx < 0) gx += WW; else if (gx >= WW) gx -= WW;
        sh[ch][ly][col] = uin_b[ch*PLANE + gy*WW + gx];
    }
    __syncthreads();

    const int cy = tid >> 5;            // 0..7
    const int x3 = (tid & 31) * 3;      // 0,3,..,93  (stride-3: conflict-free banks)

    // ---- Conv: D[px][ch][j], 16 dot products per pixel.
    float D[3][2][8];
    #pragma unroll
    for (int p = 0; p < 3; ++p)
        #pragma unroll
        for (int c = 0; c < 2; ++c)
            #pragma unroll
            for (int j = 0; j < 8; ++j)
                D[p][c][j] = 0.0f;

    #pragma unroll
    for (int c = 0; c < 2; ++c) {
        float win[5][7];
        #pragma unroll
        for (int dy = 0; dy < 5; ++dy)
            #pragma unroll
            for (int dx = 0; dx < 7; ++dx)
                win[dy][dx] = sh[c][cy+dy][x3+dx];
        #pragma unroll
        for (int o = 0; o < 25; ++o) {
            const int dy = o / 5, dx = o % 5;
            #pragma unroll
            for (int j = 0; j < 8; ++j) {
                const float w = K8T[o*8 + j];
                D[0][c][j] += win[dy][dx]   * w;
                D[1][c][j] += win[dy][dx+1] * w;
                D[2][c][j] += win[dy][dx+2] * w;
            }
        }
    }

    // Base features: Z(p,i) aliases D[p][i/6][i%6] (i compile-time const).
#define ZF(p,i) D[p][(i)/6][(i)%6]

    float xs[3][12];
    #pragma unroll
    for (int p = 0; p < 3; ++p)
        #pragma unroll
        for (int i = 0; i < 12; ++i)
            xs[p][i] = ZF(p, i);

    // ---- Upwind: analytic d(poly_k)/dz at base z, all px in lockstep.
    #pragma unroll
    for (int k = 0; k < 2; ++k) {
        const float* W0 = pw0 + k*24;   // [2][12]
        const float* B0 = pb0 + k*2;
        const float* W1 = pw1 + k*26;   // [2][13]
        const float* B1 = pb1 + k*2;
        const float* WF = pwf + k*14;   // [14]

        float o0[3], o1[3], q0[3], q1[3];
        #pragma unroll
        for (int p = 0; p < 3; ++p) { o0[p] = B0[0]; o1[p] = B0[1]; }
        #pragma unroll
        for (int i = 0; i < 12; ++i) {
            const float wa = W0[i], wb = W0[12+i];
            #pragma unroll
            for (int p = 0; p < 3; ++p) {
                o0[p] += wa * ZF(p, i);
                o1[p] += wb * ZF(p, i);
            }
        }
        #pragma unroll
        for (int p = 0; p < 3; ++p) {
            const float pp = o0[p]*o1[p];
            q0[p] = B1[0] + W1[12]*pp;
            q1[p] = B1[1] + W1[25]*pp;
        }
        #pragma unroll
        for (int i = 0; i < 12; ++i) {
            const float wa = W1[i], wb = W1[13+i];
            #pragma unroll
            for (int p = 0; p < 3; ++p) {
                q0[p] += wa * ZF(p, i);
                q1[p] += wb * ZF(p, i);
            }
        }

        const int i1 = k*6+1, i2 = k*6+2;
        #pragma unroll
        for (int p = 0; p < 3; ++p) {
            {
                const float t = o1[p]*W0[i1] + o0[p]*W0[12+i1];
                const float g = WF[i1] + WF[12]*t
                    + WF[13]*(q1[p]*(W1[i1] + W1[12]*t) + q0[p]*(W1[13+i1] + W1[25]*t));
                xs[p][i1] = (g > 0.0f) ? ZF(p, i1) : D[p][k][6];
            }
            {
                const float t = o1[p]*W0[i2] + o0[p]*W0[12+i2];
                const float g = WF[i2] + WF[12]*t
                    + WF[13]*(q1[p]*(W1[i2] + W1[12]*t) + q0[p]*(W1[13+i2] + W1[25]*t));
                xs[p][i2] = (g > 0.0f) ? ZF(p, i2) : D[p][k][7];
            }
        }
    }

    // ---- Forward poly at selected features, all px in lockstep.
    float res[3][2];   // [px][k]
    #pragma unroll
    for (int k = 0; k < 2; ++k) {
        const float* W0 = pw0 + k*24;
        const float* B0 = pb0 + k*2;
        const float* W1 = pw1 + k*26;
        const float* B1 = pb1 + k*2;
        const float* WF = pwf + k*14;
        const float* BF = pbf + k;

        float o0[3], o1[3], q0[3], q1[3], y[3];
        #pragma unroll
        for (int p = 0; p < 3; ++p) { o0[p] = B0[0]; o1[p] = B0[1]; }
        #pragma unroll
        for (int i = 0; i < 12; ++i) {
            const float wa = W0[i], wb = W0[12+i];
            #pragma unroll
            for (int p = 0; p < 3; ++p) {
                o0[p] += wa * xs[p][i];
                o1[p] += wb * xs[p][i];
            }
        }
        #pragma unroll
        for (int p = 0; p < 3; ++p) {
            const float pp = o0[p]*o1[p];
            q0[p] = B1[0] + W1[12]*pp;
            q1[p] = B1[1] + W1[25]*pp;
            y[p]  = BF[0] + WF[12]*pp;
        }
        #pragma unroll
        for (int i = 0; i < 12; ++i) {
            const float wa = W1[i], wb = W1[13+i], wc = WF[i];
            #pragma unroll
            for (int p = 0; p < 3; ++p) {
                q0[p] += wa * xs[p][i];
                q1[p] += wb * xs[p][i];
                y[p]  += wc * xs[p][i];
            }
        }
        #pragma unroll
        for (int p = 0; p < 3; ++p)
            res[p][k] = y[p] + WF[13]*(q0[p]*q1[p]);
    }

    const int oy = ty0 + cy, ox = tx0 + x3;
    const size_t o0i = (size_t)b * 2 * PLANE + (size_t)oy * WW + ox;
    float bb0[3], bb1[3];
    #pragma unroll
    for (int p = 0; p < 3; ++p) {
        bb0[p] = ubase[o0i + p];
        bb1[p] = ubase[o0i + PLANE + p];
    }
    #pragma unroll
    for (int p = 0; p < 3; ++p) {
        uout[o0i + p]         = bb0[p] + alpha * res[p][0];
        uout[o0i + PLANE + p] = bb1[p] + alpha * res[p][1];
    }
}

extern "C" void kernel_launch(void* const* d_in, const int* in_sizes, int n_in,
                              void* d_out, int out_size, void* d_ws, size_t ws_size,
                              hipStream_t stream)
{
    const float* init = (const float*)d_in[0];
    const float* kern = (const float*)d_in[1];
    const float* pw0  = (const float*)d_in[2];
    const float* pb0  = (const float*)d_in[3];
    const float* pw1  = (const float*)d_in[4];
    const float* pb1  = (const float*)d_in[5];
    const float* pwf  = (const float*)d_in[6];
    const float* pbf  = (const float*)d_in[7];
    float* out = (float*)d_out;

    float* K8T  = (float*)d_ws;        // 200 floats (padded to 256)
    float* bufA = K8T + 256;           // NELEM floats: u_n
    float* bufH = bufA + NELEM;        // NELEM floats: u_half

    prep_kernel<<<dim3(1), dim3(256), 0, stream>>>(kern, K8T);

    const dim3 grid(WW/TILEX, HH/TILEY, BATCH);   // (2, 24, 16) = 768 blocks
    const dim3 block(256);
    const float DTF = 0.2f, DTH = 0.1f;

    // T=1 -> 5 RK2 (midpoint) steps, 2 RHS evals each (sequential dependency).
    rhs_kernel<<<grid, block, 0, stream>>>(init, init, bufH, K8T, pw0,pb0,pw1,pb1,pwf,pbf, DTH);
    rhs_kernel<<<grid, block, 0, stream>>>(bufH, init, bufA, K8T, pw0,pb0,pw1,pb1,pwf,pbf, DTF);
    for (int s = 0; s < 3; ++s) {
        rhs_kernel<<<grid, block, 0, stream>>>(bufA, bufA, bufH, K8T, pw0,pb0,pw1,pb1,pwf,pbf, DTH);
        rhs_kernel<<<grid, block, 0, stream>>>(bufH, bufA, bufA, K8T, pw0,pb0,pw1,pb1,pwf,pbf, DTF);
    }
    rhs_kernel<<<grid, block, 0, stream>>>(bufA, bufA, bufH, K8T, pw0,pb0,pw1,pb1,pwf,pbf, DTH);
    rhs_kernel<<<grid, block, 0, stream>>>(bufH, bufA, out,  K8T, pw0,pb0,pw1,pb1,pwf,pbf, DTF);
}

// Round 2
// 246.488 us; speedup vs baseline: 1.0040x; 1.0040x over previous
//
#include <hip/hip_runtime.h>

#define HH 192
#define WW 192
#define BATCH 16
#define PLANE (HH*WW)              /* 36864 */
#define NELEM (BATCH*2*PLANE)      /* 1179648 */

// Tile: 96 px wide x 8 rows, 256 threads, 3 px per thread. Halo 2 each side.
// Grid = (2,24,16) = 768 blocks = exactly 3 blocks/CU at launch_bounds(256,3).
#define TILEX 96
#define TILEY 8
#define SW 100  /* TILEX + 4 */
#define SH2 12  /* TILEY + 4 */
#define NSTAGE (2*SH2*SW)   /* 2400 */

// K8T layout: tap-major [25][8] so the 8 per-tap weights are contiguous
// (one s_load_dwordx8). j<6: kernels[j]*DX^-ord; j==6: -K[1] x-flip;
// j==7: -K[2] y-flip.
__global__ void prep_kernel(const float* __restrict__ kern, float* __restrict__ K8T) {
    int t = blockIdx.x * blockDim.x + threadIdx.x;
    if (t >= 200) return;
    const float inv  = 1.0f / 0.0327249f;
    const float inv2 = inv * inv;
    const float sc[6] = {1.0f, inv, inv, inv2, inv2, inv2};
    int o = t / 8, j = t % 8, dy = o / 5, dx = o % 5;
    float v;
    if (j < 6)       v =  kern[j*25 + dy*5 + dx] * sc[j];
    else if (j == 6) v = -kern[1*25 + dy*5 + (4-dx)] * sc[1];
    else             v = -kern[2*25 + (4-dy)*5 + dx] * sc[2];
    K8T[o*8 + j] = v;
}

// One RHS eval fused with axpy: uout = ubase + alpha * rhs(uin).
// CODE-SIZE-MINIMIZED version: the dy loop of the conv and the k loop of the
// poly passes are ROLLED (#pragma unroll 1) so the kernel body is ~7 KB
// instead of ~30 KB of straight-line code (I$-thrash theory). All register
// arrays (D, xs, row, o/q/y) keep compile-time indices -> no scratch.
__global__ __launch_bounds__(256, 3) void rhs_kernel(
    const float* __restrict__ uin,
    const float* __restrict__ ubase,
    float* __restrict__ uout,
    const float* __restrict__ K8T,
    const float* __restrict__ pw0, const float* __restrict__ pb0,
    const float* __restrict__ pw1, const float* __restrict__ pb1,
    const float* __restrict__ pwf, const float* __restrict__ pbf,
    float alpha)
{
    __shared__ float sh[2][SH2][SW];
    const int b   = blockIdx.z;
    const int ty0 = blockIdx.y * TILEY;
    const int tx0 = blockIdx.x * TILEX;
    const int tid = threadIdx.x;

    const float* uin_b = uin + (size_t)b * 2 * PLANE;

    // ---- Staging: 2400 elems over 256 threads (9-10 each).
    for (int i = tid; i < NSTAGE; i += 256) {
        const int ch  = (i >= SH2*SW) ? 1 : 0;
        const int j   = i - ch * (SH2*SW);
        const int ly  = j / SW;
        const int col = j - ly * SW;
        int gy = ty0 + ly - 2;  if (gy < 0) gy += HH; else if (gy >= HH) gy -= HH;
        int gx = tx0 + col - 2; if (gx < 0) gx += WW; else if (gx >= WW) gx -= WW;
        sh[ch][ly][col] = uin_b[ch*PLANE + gy*WW + gx];
    }
    __syncthreads();

    const int cy = tid >> 5;            // 0..7
    const int x3 = (tid & 31) * 3;      // 0,3,..,93

    // ---- Conv: D[px][ch][j], 16 dot products per pixel. dy loop ROLLED.
    float D[3][2][8];
    #pragma unroll
    for (int p = 0; p < 3; ++p)
        #pragma unroll
        for (int c = 0; c < 2; ++c)
            #pragma unroll
            for (int j = 0; j < 8; ++j)
                D[p][c][j] = 0.0f;

    #pragma unroll
    for (int c = 0; c < 2; ++c) {
        #pragma unroll 1
        for (int dy = 0; dy < 5; ++dy) {
            float row[7];
            #pragma unroll
            for (int dx = 0; dx < 7; ++dx)
                row[dx] = sh[c][cy + dy][x3 + dx];
            const float* Kt = K8T + dy * 40;   // 5 taps x 8 weights
            #pragma unroll
            for (int dx = 0; dx < 5; ++dx) {
                #pragma unroll
                for (int j = 0; j < 8; ++j) {
                    const float w = Kt[dx*8 + j];
                    D[0][c][j] += row[dx]   * w;
                    D[1][c][j] += row[dx+1] * w;
                    D[2][c][j] += row[dx+2] * w;
                }
            }
        }
    }

    // Base features: Z(p,i) aliases D[p][i/6][i%6] (i compile-time const).
#define ZF(p,i) D[p][(i)/6][(i)%6]

    float xs[3][12];
    #pragma unroll
    for (int p = 0; p < 3; ++p)
        #pragma unroll
        for (int i = 0; i < 12; ++i)
            xs[p][i] = ZF(p, i);

    // ---- Upwind: analytic d(poly_k)/dz at base z. k loop ROLLED; the only
    // k-dependent register-array accesses live in uniform if/else arms with
    // constant indices.
    #pragma unroll 1
    for (int k = 0; k < 2; ++k) {
        const float* W0 = pw0 + k*24;   // [2][12]
        const float* B0 = pb0 + k*2;
        const float* W1 = pw1 + k*26;   // [2][13]
        const float* B1 = pb1 + k*2;
        const float* WF = pwf + k*14;   // [14]
        const int i1 = k*6 + 1, i2 = k*6 + 2;   // runtime scalar offsets (loads only)

        float o0[3], o1[3], q0[3], q1[3];
        #pragma unroll
        for (int p = 0; p < 3; ++p) { o0[p] = B0[0]; o1[p] = B0[1]; }
        #pragma unroll
        for (int i = 0; i < 12; ++i) {
            const float wa = W0[i], wb = W0[12+i];
            #pragma unroll
            for (int p = 0; p < 3; ++p) {
                o0[p] += wa * ZF(p, i);
                o1[p] += wb * ZF(p, i);
            }
        }
        #pragma unroll
        for (int p = 0; p < 3; ++p) {
            const float pp = o0[p]*o1[p];
            q0[p] = B1[0] + W1[12]*pp;
            q1[p] = B1[1] + W1[25]*pp;
        }
        #pragma unroll
        for (int i = 0; i < 12; ++i) {
            const float wa = W1[i], wb = W1[13+i];
            #pragma unroll
            for (int p = 0; p < 3; ++p) {
                q0[p] += wa * ZF(p, i);
                q1[p] += wb * ZF(p, i);
            }
        }

        // Gradients at the two upwind-selectable features (scalar-weight loads
        // with runtime offsets are fine; no register-array runtime indexing).
        const float w0a1 = W0[i1], w0b1 = W0[12+i1];
        const float w1a1 = W1[i1], w1b1 = W1[13+i1];
        const float wf1  = WF[i1];
        const float w0a2 = W0[i2], w0b2 = W0[12+i2];
        const float w1a2 = W1[i2], w1b2 = W1[13+i2];
        const float wf2  = WF[i2];
        const float w112 = W1[12], w125 = W1[25], wf12 = WF[12], wf13 = WF[13];

        float g1[3], g2[3];
        #pragma unroll
        for (int p = 0; p < 3; ++p) {
            {
                const float t = o1[p]*w0a1 + o0[p]*w0b1;
                g1[p] = wf1 + wf12*t
                    + wf13*(q1[p]*(w1a1 + w112*t) + q0[p]*(w1b1 + w125*t));
            }
            {
                const float t = o1[p]*w0a2 + o0[p]*w0b2;
                g2[p] = wf2 + wf12*t
                    + wf13*(q1[p]*(w1a2 + w112*t) + q0[p]*(w1b2 + w125*t));
            }
        }

        if (k == 0) {
            #pragma unroll
            for (int p = 0; p < 3; ++p) {
                xs[p][1] = (g1[p] > 0.0f) ? xs[p][1] : D[p][0][6];
                xs[p][2] = (g2[p] > 0.0f) ? xs[p][2] : D[p][0][7];
            }
        } else {
            #pragma unroll
            for (int p = 0; p < 3; ++p) {
                xs[p][7] = (g1[p] > 0.0f) ? xs[p][7] : D[p][1][6];
                xs[p][8] = (g2[p] > 0.0f) ? xs[p][8] : D[p][1][7];
            }
        }
    }

    // ---- Forward poly at selected features. k loop ROLLED.
    float res0[3], res1[3];
    #pragma unroll 1
    for (int k = 0; k < 2; ++k) {
        const float* W0 = pw0 + k*24;
        const float* B0 = pb0 + k*2;
        const float* W1 = pw1 + k*26;
        const float* B1 = pb1 + k*2;
        const float* WF = pwf + k*14;
        const float* BF = pbf + k;

        float o0[3], o1[3], q0[3], q1[3], y[3];
        #pragma unroll
        for (int p = 0; p < 3; ++p) { o0[p] = B0[0]; o1[p] = B0[1]; }
        #pragma unroll
        for (int i = 0; i < 12; ++i) {
            const float wa = W0[i], wb = W0[12+i];
            #pragma unroll
            for (int p = 0; p < 3; ++p) {
                o0[p] += wa * xs[p][i];
                o1[p] += wb * xs[p][i];
            }
        }
        #pragma unroll
        for (int p = 0; p < 3; ++p) {
            const float pp = o0[p]*o1[p];
            q0[p] = B1[0] + W1[12]*pp;
            q1[p] = B1[1] + W1[25]*pp;
            y[p]  = BF[0] + WF[12]*pp;
        }
        #pragma unroll
        for (int i = 0; i < 12; ++i) {
            const float wa = W1[i], wb = W1[13+i], wc = WF[i];
            #pragma unroll
            for (int p = 0; p < 3; ++p) {
                q0[p] += wa * xs[p][i];
                q1[p] += wb * xs[p][i];
                y[p]  += wc * xs[p][i];
            }
        }
        const float wf13 = WF[13];
        if (k == 0) {
            #pragma unroll
            for (int p = 0; p < 3; ++p) res0[p] = y[p] + wf13*(q0[p]*q1[p]);
        } else {
            #pragma unroll
            for (int p = 0; p < 3; ++p) res1[p] = y[p] + wf13*(q0[p]*q1[p]);
        }
    }

    const int oy = ty0 + cy, ox = tx0 + x3;
    const size_t o0i = (size_t)b * 2 * PLANE + (size_t)oy * WW + ox;
    float bb0[3], bb1[3];
    #pragma unroll
    for (int p = 0; p < 3; ++p) {
        bb0[p] = ubase[o0i + p];
        bb1[p] = ubase[o0i + PLANE + p];
    }
    #pragma unroll
    for (int p = 0; p < 3; ++p) {
        uout[o0i + p]         = bb0[p] + alpha * res0[p];
        uout[o0i + PLANE + p] = bb1[p] + alpha * res1[p];
    }
}

extern "C" void kernel_launch(void* const* d_in, const int* in_sizes, int n_in,
                              void* d_out, int out_size, void* d_ws, size_t ws_size,
                              hipStream_t stream)
{
    const float* init = (const float*)d_in[0];
    const float* kern = (const float*)d_in[1];
    const float* pw0  = (const float*)d_in[2];
    const float* pb0  = (const float*)d_in[3];
    const float* pw1  = (const float*)d_in[4];
    const float* pb1  = (const float*)d_in[5];
    const float* pwf  = (const float*)d_in[6];
    const float* pbf  = (const float*)d_in[7];
    float* out = (float*)d_out;

    float* K8T  = (float*)d_ws;        // 200 floats (padded to 256)
    float* bufA = K8T + 256;           // NELEM floats: u_n
    float* bufH = bufA + NELEM;        // NELEM floats: u_half

    prep_kernel<<<dim3(1), dim3(256), 0, stream>>>(kern, K8T);

    const dim3 grid(WW/TILEX, HH/TILEY, BATCH);   // (2, 24, 16) = 768 blocks
    const dim3 block(256);
    const float DTF = 0.2f, DTH = 0.1f;

    // T=1 -> 5 RK2 (midpoint) steps, 2 RHS evals each (sequential dependency).
    rhs_kernel<<<grid, block, 0, stream>>>(init, init, bufH, K8T, pw0,pb0,pw1,pb1,pwf,pbf, DTH);
    rhs_kernel<<<grid, block, 0, stream>>>(bufH, init, bufA, K8T, pw0,pb0,pw1,pb1,pwf,pbf, DTF);
    for (int s = 0; s < 3; ++s) {
        rhs_kernel<<<grid, block, 0, stream>>>(bufA, bufA, bufH, K8T, pw0,pb0,pw1,pb1,pwf,pbf, DTH);
        rhs_kernel<<<grid, block, 0, stream>>>(bufH, bufA, bufA, K8T, pw0,pb0,pw1,pb1,pwf,pbf, DTF);
    }
    rhs_kernel<<<grid, block, 0, stream>>>(bufA, bufA, bufH, K8T, pw0,pb0,pw1,pb1,pwf,pbf, DTH);
    rhs_kernel<<<grid, block, 0, stream>>>(bufH, bufA, out,  K8T, pw0,pb0,pw1,pb1,pwf,pbf, DTF);
}